// Round 9
// baseline (338.521 us; speedup 1.0000x reference)
//
#include <hip/hip_runtime.h>
#include <stdint.h>

#define DMODEL 1024
#define NHEADS 16
#define DKH 64
#define BATCH 2
#define SEQ 2048
#define MTOT (BATCH*SEQ)   // 4096

typedef __bf16 bf16x8 __attribute__((ext_vector_type(8)));
typedef __bf16 bf16x4 __attribute__((ext_vector_type(4)));
typedef float  f32x4  __attribute__((ext_vector_type(4)));

__device__ __forceinline__ f32x4 mfma16(bf16x8 a, bf16x8 b, f32x4 c){
  return __builtin_amdgcn_mfma_f32_16x16x32_bf16(a, b, c, 0, 0, 0);
}

// async global->LDS, 16B per lane. LDS dest wave-uniform base; lane i lands at base + i*16.
__device__ __forceinline__ void gload_lds16(const void* g, void* l){
  __builtin_amdgcn_global_load_lds(
      (const __attribute__((address_space(1))) uint32_t*)(uintptr_t)g,
      (__attribute__((address_space(3))) uint32_t*)(uint32_t)(uintptr_t)l,
      16, 0, 0);
}

__device__ __forceinline__ unsigned short f2bf(float f){
  unsigned u = __builtin_bit_cast(unsigned, f);
  u += 0x7fff + ((u >> 16) & 1);          // round-to-nearest-even
  return (unsigned short)(u >> 16);
}

// scale * log2(e), folded into Q at the QKV epilogue
#define QSCALE 0.1803368801111372f        // 0.125 * 1.4426950408889634

// ---------------- fused fp32 -> bf16 convert (x, W_qkv, W_out in one launch) ----------------
__global__ void cvt3_kernel(const float* __restrict__ a, const float* __restrict__ b,
                            const float* __restrict__ c,
                            unsigned short* __restrict__ oa, unsigned short* __restrict__ ob,
                            unsigned short* __restrict__ oc,
                            int na4, int nb4, int nc4){
  int i = blockIdx.x * blockDim.x + threadIdx.x;
  const int tot = na4 + nb4 + nc4;
  const int stride = gridDim.x * blockDim.x;
  for (; i < tot; i += stride){
    const float4* s; ushort4* d; int k;
    if (i < na4)            { s = (const float4*)a; d = (ushort4*)oa; k = i; }
    else if (i < na4 + nb4) { s = (const float4*)b; d = (ushort4*)ob; k = i - na4; }
    else                    { s = (const float4*)c; d = (ushort4*)oc; k = i - na4 - nb4; }
    float4 v = s[k];
    ushort4 o;
    o.x = f2bf(v.x); o.y = f2bf(v.y); o.z = f2bf(v.z); o.w = f2bf(v.w);
    d[k] = o;
  }
}

// ---------------- GEMM: C[m,n] = sum_k A[m,k]*B[n,k]  (B^T layout) ----------------
// Single-barrier double-buffered staging; 1D grid with XCD-confinement swizzle.
// EPI==0 (128x128): Q (pre-scaled) / K direct scatter; V via LDS-transpose ->
//                   fully coalesced Vt row stores.
// EPI==1 (128x64):  fp32 coalesced store to Co.
template<int EPI, int BM, int BN, int NBN>
__global__ __launch_bounds__(256)
void gemm_bt(const __bf16* __restrict__ Ag, const __bf16* __restrict__ Bg,
             int M, int N, int K,
             __bf16* __restrict__ Qo, __bf16* __restrict__ Ko, __bf16* __restrict__ Vt,
             float* __restrict__ Co){
  constexpr int AM = BM/32;          // A fragments per wave
  constexpr int AN = BN/32;          // B fragments per wave
  constexpr int CA = BM/64;          // A staging chunks per wave
  constexpr int CB = BN/64;          // B staging chunks per wave
  __shared__ __align__(16) __bf16 As[2][BM*32];
  __shared__ __align__(16) __bf16 Bs[2][BN*32];
  const int tid  = threadIdx.x;
  const int wave = tid >> 6, lane = tid & 63;
  const int wr = wave >> 1, wc = wave & 1;
  const int lr = lane & 15, lg = lane >> 4;

  const int id  = blockIdx.x;
  const int xcd = id & 7;
  const int idx = id >> 3;
  const int m0  = (xcd*4 + idx/NBN) * BM;
  const int n0  = (idx % NBN) * BN;

  f32x4 acc[AM][AN] = {};

  const int srow = lane >> 2;        // 0..15
  const int scol = (lane & 3) * 8;   // 0,8,16,24
  const __bf16* gA = Ag + (size_t)(m0 + wave*(BM/4) + srow) * K + scol;
  const __bf16* gB = Bg + (size_t)(n0 + wave*(BN/4) + srow) * K + scol;

  const int nk = K >> 5;

  // prologue: stage k-step 0 into buf 0
#pragma unroll
  for (int c = 0; c < CA; c++)
    gload_lds16(gA + (size_t)(c*16)*K, &As[0][(wave*(BM/4) + c*16)*32]);
#pragma unroll
  for (int c = 0; c < CB; c++)
    gload_lds16(gB + (size_t)(c*16)*K, &Bs[0][(wave*(BN/4) + c*16)*32]);

  for (int t = 0; t < nk; t++){
    __syncthreads();                 // drains stage of buf[t&1] (hidden under prev compute)
    if (t + 1 < nk){
      const int k0 = (t+1) << 5, bb = (t+1) & 1;
#pragma unroll
      for (int c = 0; c < CA; c++)
        gload_lds16(gA + k0 + (size_t)(c*16)*K, &As[bb][(wave*(BM/4) + c*16)*32]);
#pragma unroll
      for (int c = 0; c < CB; c++)
        gload_lds16(gB + k0 + (size_t)(c*16)*K, &Bs[bb][(wave*(BN/4) + c*16)*32]);
    }
    const int cb = t & 1;
    bf16x8 af[AM], bfv[AN];
#pragma unroll
    for (int i = 0; i < AM; i++)
      af[i] = *(const bf16x8*)&As[cb][(wr*(BM/2) + i*16 + lr)*32 + lg*8];
#pragma unroll
    for (int j = 0; j < AN; j++)
      bfv[j] = *(const bf16x8*)&Bs[cb][(wc*(BN/2) + j*16 + lr)*32 + lg*8];
#pragma unroll
    for (int i = 0; i < AM; i++)
#pragma unroll
      for (int j = 0; j < AN; j++)
        acc[i][j] = mfma16(af[i], bfv[j], acc[i][j]);
  }

  if (EPI == 0){
    const int three = n0 >> 10;      // block-uniform: 0=Q, 1=K, 2=V
    if (three < 2){
#pragma unroll
      for (int i = 0; i < AM; i++){
#pragma unroll
        for (int j = 0; j < AN; j++){
#pragma unroll
          for (int r = 0; r < 4; r++){
            int m = m0 + wr*(BM/2) + i*16 + lg*4 + r;
            int n = n0 + wc*(BN/2) + j*16 + lr;
            int b = m >> 11, s = m & 2047;
            int h = (n >> 6) & 15, dk = n & 63;
            if (three == 0) Qo[(((size_t)(b*NHEADS + h))*SEQ + s)*DKH + dk] = (__bf16)(acc[i][j][r] * QSCALE);
            else            Ko[(((size_t)(b*NHEADS + h))*SEQ + s)*DKH + dk] = (__bf16)acc[i][j][r];
          }
        }
      }
    } else {
      // V: route acc through LDS, store Vt rows coalesced (32B runs).
      __bf16 (*T)[136] = (__bf16(*)[136])&As[0][0];      // [32 n][128 m] bf16, stride 136
      const int lrow = tid >> 3;          // 0..31 (LDS tile row on read side)
      const int mc   = (tid & 7) * 16;    // m-col base on read side
      const int ngr  = (n0 - 2048) + ((lrow >> 4) << 6) + (lrow & 15);  // + j*16 per chunk
      const int bb   = m0 >> 11;
      const int sbase= (m0 & 2047) + mc;
#pragma unroll
      for (int j = 0; j < AN; j++){
        __syncthreads();                  // prev chunk read done / k-loop LDS reads done
#pragma unroll
        for (int i = 0; i < AM; i++){
          bf16x4 v;
#pragma unroll
          for (int r = 0; r < 4; r++) v[r] = (__bf16)acc[i][j][r];
          *(bf16x4*)&T[wc*16 + lr][wr*64 + i*16 + lg*4] = v;
        }
        __syncthreads();
        const int ng = ngr + j*16;        // 0..1023 within V third
        __bf16* dst = Vt + (((size_t)(bb*NHEADS) + (ng >> 6))*DKH + (ng & 63))*SEQ + sbase;
        bf16x8 x0 = *(const bf16x8*)&T[lrow][mc];
        bf16x8 x1 = *(const bf16x8*)&T[lrow][mc + 8];
        *(bf16x8*)dst = x0;
        *(bf16x8*)(dst + 8) = x1;
      }
    }
  } else {
#pragma unroll
    for (int i = 0; i < AM; i++)
#pragma unroll
      for (int j = 0; j < AN; j++)
#pragma unroll
        for (int r = 0; r < 4; r++){
          int m = m0 + wr*(BM/2) + i*16 + lg*4 + r;
          int n = n0 + wc*(BN/2) + j*16 + lr;
          Co[(size_t)m * N + n] = acc[i][j][r];
        }
  }
}

// ---------------- causal flash attention: 1-tile blocks, reg-staged single LDS buffer ----
// Q (pre-scaled), K: [b,h,s,dk] bf16; Vt: [b,h,dk,s] bf16; Aout: [b,s,h*64+dk] bf16
// 2048 blocks x 2 waves; block = one 32-row q-tile (big-first), XCD-confined (64
// blocks of each bh on one XCD; per-XCD set 3MB < 4MB L2). LDS 16KB/block ->
// 8 blocks/CU = 16 waves/CU (2x R8's TLP). T14 reg-staging: next tile's K/V
// global loads issued into 32 VGPR right after this tile's ds_writes; latency
// hides under compute. Write-side swizzle col^((row&7)<<4); read side unchanged.
// l via ones-column MFMA (lac) — no per-lane adds, no epilogue shuffles.
__global__ __launch_bounds__(128, 4)
void attn_kernel(const __bf16* __restrict__ Q, const __bf16* __restrict__ K,
                 const __bf16* __restrict__ Vt, __bf16* __restrict__ Aout){
  const int id   = blockIdx.x;               // 0..2047
  const int xcd  = id & 7;
  const int slot = id >> 3;                  // 0..255
  const int bh   = (xcd << 2) | (slot >> 6); // 4 bh per XCD
  const int tb   = 63 - (slot & 63);         // 32-row q-tile, big tiles first
  const int wave = threadIdx.x >> 6, lane = threadIdx.x & 63;
  const int lr = lane & 15, lg = lane >> 4;
  const int swz = (lr & 7) << 4;             // read-side XOR

  const __bf16* Qh = Q + (size_t)bh*SEQ*DKH;
  const char* Kc = (const char*)(K  + (size_t)bh*SEQ*DKH);   // row stride 128B
  const char* Vc = (const char*)(Vt + (size_t)bh*DKH*SEQ);   // row stride 4096B

  __shared__ __align__(16) char lds[16384];  // K 8KB | V 8KB (single buffer)

  const int row8 = lane >> 3;                // 0..7
  const int cL   = (lane & 7) << 4;          // linear 16B chunk
  const int cW   = cL ^ (row8 << 4);         // write-side swizzled chunk

  const int b = bh >> 4, h = bh & 15;
  const int qw  = tb*32 + wave*16;           // wave's first q row
  const int nkv = (tb >> 1) + 1;             // kv tiles of 64 covering tile rows

  bf16x8 qf0 = *(const bf16x8*)(Qh + (size_t)(qw + lr)*DKH + lg*8);
  bf16x8 qf1 = *(const bf16x8*)(Qh + (size_t)(qw + lr)*DKH + 32 + lg*8);

  bf16x8 ONE8;
#pragma unroll
  for (int i = 0; i < 8; i++) ONE8[i] = (__bf16)1.0f;

  f32x4 o[4] = {};
  f32x4 lac = {};                            // row-sum accumulator (ones-column MFMA)
  float mrun = -1e30f;

  // staging registers (tile kb data in flight)
  int4 kr[4], vr[4];
#pragma unroll
  for (int c = 0; c < 4; c++){
    const int row = wave*32 + c*8 + row8;
    kr[c] = *(const int4*)(Kc + (size_t)row*128 + cL);
    vr[c] = *(const int4*)(Vc + (size_t)row*4096 + cL);
  }

  for (int kb = 0; kb < nkv; kb++){
    const int kv0 = kb*64;
    __syncthreads();                         // all waves done reading lds (prev round)
#pragma unroll
    for (int c = 0; c < 4; c++){             // waits vmcnt for kr/vr implicitly
      const int row = wave*32 + c*8 + row8;
      *(int4*)(&lds[row*128 + cW]) = kr[c];
      *(int4*)(&lds[8192 + row*128 + cW]) = vr[c];
    }
    if (kb + 1 < nkv){                       // issue next tile's loads (hide under compute)
      const int nv0 = kv0 + 64;
#pragma unroll
      for (int c = 0; c < 4; c++){
        const int row = wave*32 + c*8 + row8;
        kr[c] = *(const int4*)(Kc + (size_t)(nv0 + row)*128 + cL);
        vr[c] = *(const int4*)(Vc + (size_t)row*4096 + (size_t)nv0*2 + cL);
      }
    }
    __syncthreads();                         // lds visible
    const char* Ks = lds;
    const char* Vs = lds + 8192;

    // ---- QK^T (swapped): sf[t][r] = S[kv0+t*16+lg*4+r][qw+lr] (exp2-domain)
    f32x4 sf[4];
    __builtin_amdgcn_s_setprio(1);
#pragma unroll
    for (int t = 0; t < 4; t++){
      const int row = t*16 + lr;
      bf16x8 kf0 = *(const bf16x8*)(Ks + row*128 + ((lg*16) ^ swz));
      bf16x8 kf1 = *(const bf16x8*)(Ks + row*128 + ((64 + lg*16) ^ swz));
      f32x4 c = {};
      c = mfma16(kf0, qf0, c);
      c = mfma16(kf1, qf1, c);
      sf[t] = c;
    }
    __builtin_amdgcn_s_setprio(0);
    // ---- causal mask (diagonal tiles only)
    if (kv0 + 63 > qw){
      const int q = qw + lr;
#pragma unroll
      for (int t = 0; t < 4; t++)
#pragma unroll
        for (int r = 0; r < 4; r++){
          int kv = kv0 + t*16 + lg*4 + r;
          sf[t][r] = (kv <= q) ? sf[t][r] : -1e30f;
        }
    }
    // ---- row max (max3-friendly tree), then across 4 lanes sharing q-row lr
    float ma = fmaxf(fmaxf(sf[0][0], sf[0][1]), sf[0][2]);
    float mb = fmaxf(fmaxf(sf[0][3], sf[1][0]), sf[1][1]);
    float mc = fmaxf(fmaxf(sf[1][2], sf[1][3]), sf[2][0]);
    float md = fmaxf(fmaxf(sf[2][1], sf[2][2]), sf[2][3]);
    float me = fmaxf(fmaxf(sf[3][0], sf[3][1]), sf[3][2]);
    float mx = fmaxf(fmaxf(ma, mb), mc);
    mx = fmaxf(fmaxf(mx, md), me);
    mx = fmaxf(mx, sf[3][3]);
    mx = fmaxf(mx, __shfl_xor(mx, 16));
    mx = fmaxf(mx, __shfl_xor(mx, 32));

    // ---- T13 defer-rescale: keep old max when growth <= 8 (P <= 2^8, bf16-safe)
    if (!__all(mx <= mrun + 8.0f)){
      float mn = fmaxf(mrun, mx);
      float alpha = __builtin_amdgcn_exp2f(mrun - mn);
      mrun = mn;
      float av[4];
#pragma unroll
      for (int r = 0; r < 4; r++) av[r] = __shfl(alpha, lg*4 + r);
#pragma unroll
      for (int n = 0; n < 4; n++)
#pragma unroll
        for (int r = 0; r < 4; r++) o[n][r] *= av[r];
#pragma unroll
      for (int r = 0; r < 4; r++) lac[r] *= av[r];
    }

    // ---- P = exp2(s-m) packed straight to bf16 A-fragments
    bf16x8 pa0, pa1;
#pragma unroll
    for (int t = 0; t < 2; t++)
#pragma unroll
      for (int r = 0; r < 4; r++)
        pa0[t*4 + r] = (__bf16)__builtin_amdgcn_exp2f(sf[t][r] - mrun);
#pragma unroll
    for (int t = 0; t < 2; t++)
#pragma unroll
      for (int r = 0; r < 4; r++)
        pa1[t*4 + r] = (__bf16)__builtin_amdgcn_exp2f(sf[t+2][r] - mrun);

    // ---- PV + row-sum via ones-column MFMA
    __builtin_amdgcn_s_setprio(1);
    lac = mfma16(pa0, ONE8, lac);
    lac = mfma16(pa1, ONE8, lac);
#pragma unroll
    for (int n = 0; n < 4; n++){
      const int row = n*16 + lr;
      bf16x4 vlo0 = *(const bf16x4*)(Vs + row*128 + ((lg*8) ^ swz));
      bf16x4 vhi0 = *(const bf16x4*)(Vs + row*128 + ((32 + lg*8) ^ swz));
      bf16x4 vlo1 = *(const bf16x4*)(Vs + row*128 + ((64 + lg*8) ^ swz));
      bf16x4 vhi1 = *(const bf16x4*)(Vs + row*128 + ((96 + lg*8) ^ swz));
      bf16x8 vf0 = __builtin_shufflevector(vlo0, vhi0, 0,1,2,3,4,5,6,7);
      bf16x8 vf1 = __builtin_shufflevector(vlo1, vhi1, 0,1,2,3,4,5,6,7);
      o[n] = mfma16(pa0, vf0, o[n]);
      o[n] = mfma16(pa1, vf1, o[n]);
    }
    __builtin_amdgcn_s_setprio(0);
  }

  // ---- epilogue: lac[r] holds the row sum for q = qw+lg*4+r (uniform across lr)
#pragma unroll
  for (int r = 0; r < 4; r++){
    float invr = 1.0f / lac[r];
    __bf16* dst = Aout + ((size_t)b*SEQ + qw + lg*4 + r)*DMODEL + h*DKH;
#pragma unroll
    for (int n = 0; n < 4; n++)
      dst[n*16 + lr] = (__bf16)(o[n][r] * invr);
  }
}

// ---------------- launch ----------------
extern "C" void kernel_launch(void* const* d_in, const int* in_sizes, int n_in,
                              void* d_out, int out_size, void* d_ws, size_t ws_size,
                              hipStream_t stream){
  const float* x    = (const float*)d_in[0];
  const float* wqkv = (const float*)d_in[1];
  const float* wout = (const float*)d_in[2];
  float* out = (float*)d_out;
  char* ws = (char*)d_ws;

  __bf16* xb  = (__bf16*)(ws);                    //  8,388,608  x bf16 [4096,1024]
  __bf16* Ab  = (__bf16*)(ws);                    //  attn out bf16 (alias, x dead)
  __bf16* wqb = (__bf16*)(ws + 8388608);          //  6,291,456  W_qkv bf16
  __bf16* wob = (__bf16*)(ws + 14680064);         //  2,097,152  W_out bf16
  __bf16* Qb  = (__bf16*)(ws + 16777216);         //  8,388,608  Q [b,h,s,dk] (pre-scaled)
  __bf16* Kb  = (__bf16*)(ws + 25165824);         //  8,388,608  K [b,h,s,dk]
  __bf16* Vtb = (__bf16*)(ws + 33554432);         //  8,388,608  V^T [b,h,dk,s]

  cvt3_kernel<<<2048, 256, 0, stream>>>(x, wqkv, wout,
                                        (unsigned short*)xb, (unsigned short*)wqb, (unsigned short*)wob,
                                        (MTOT*DMODEL)/4, (3*DMODEL*DMODEL)/4, (DMODEL*DMODEL)/4);

  gemm_bt<0,128,128,24><<<768, 256, 0, stream>>>(xb, wqb, MTOT, 3*DMODEL, DMODEL,
                                                 Qb, Kb, Vtb, nullptr);
  attn_kernel<<<2048, 128, 0, stream>>>(Qb, Kb, Vtb, Ab);
  gemm_bt<1,128,64,16><<<512, 256, 0, stream>>>(Ab, wob, MTOT, DMODEL, DMODEL,
                                                nullptr, nullptr, nullptr, out);
}

// Round 10
// 178.773 us; speedup vs baseline: 1.8936x; 1.8936x over previous
//
#include <hip/hip_runtime.h>
#include <stdint.h>

#define DMODEL 1024
#define NHEADS 16
#define DKH 64
#define BATCH 2
#define SEQ 2048
#define MTOT (BATCH*SEQ)   // 4096

typedef __bf16 bf16x8 __attribute__((ext_vector_type(8)));
typedef __bf16 bf16x4 __attribute__((ext_vector_type(4)));
typedef float  f32x4  __attribute__((ext_vector_type(4)));

__device__ __forceinline__ f32x4 mfma16(bf16x8 a, bf16x8 b, f32x4 c){
  return __builtin_amdgcn_mfma_f32_16x16x32_bf16(a, b, c, 0, 0, 0);
}

// async global->LDS, 16B per lane. LDS dest wave-uniform base; lane i lands at base + i*16.
__device__ __forceinline__ void gload_lds16(const void* g, void* l){
  __builtin_amdgcn_global_load_lds(
      (const __attribute__((address_space(1))) uint32_t*)(uintptr_t)g,
      (__attribute__((address_space(3))) uint32_t*)(uint32_t)(uintptr_t)l,
      16, 0, 0);
}

__device__ __forceinline__ unsigned short f2bf(float f){
  unsigned u = __builtin_bit_cast(unsigned, f);
  u += 0x7fff + ((u >> 16) & 1);          // round-to-nearest-even
  return (unsigned short)(u >> 16);
}

// scale * log2(e), folded into Q at the QKV epilogue
#define QSCALE 0.1803368801111372f        // 0.125 * 1.4426950408889634

// ---------------- fused fp32 -> bf16 convert (x, W_qkv, W_out in one launch) ----------------
__global__ void cvt3_kernel(const float* __restrict__ a, const float* __restrict__ b,
                            const float* __restrict__ c,
                            unsigned short* __restrict__ oa, unsigned short* __restrict__ ob,
                            unsigned short* __restrict__ oc,
                            int na4, int nb4, int nc4){
  int i = blockIdx.x * blockDim.x + threadIdx.x;
  const int tot = na4 + nb4 + nc4;
  const int stride = gridDim.x * blockDim.x;
  for (; i < tot; i += stride){
    const float4* s; ushort4* d; int k;
    if (i < na4)            { s = (const float4*)a; d = (ushort4*)oa; k = i; }
    else if (i < na4 + nb4) { s = (const float4*)b; d = (ushort4*)ob; k = i - na4; }
    else                    { s = (const float4*)c; d = (ushort4*)oc; k = i - na4 - nb4; }
    float4 v = s[k];
    ushort4 o;
    o.x = f2bf(v.x); o.y = f2bf(v.y); o.z = f2bf(v.z); o.w = f2bf(v.w);
    d[k] = o;
  }
}

// ---------------- GEMM: C[m,n] = sum_k A[m,k]*B[n,k]  (B^T layout) ----------------
// Single-barrier double-buffered staging; 1D grid, XCD-confined with L2-chunked
// ordering: per XCD, n-chunks of CW n-blocks x 4 m-rows (working set = CW*BN*K*2
// + 4*BM*K*2 bytes; QKV: 2MB B + 1MB A = 3MB < 4MB L2 -> B fetched once/chunk).
// idx -> nc = idx/(4*CW), mm = (idx%(4*CW))/CW, nn = idx%CW (bijective).
// EPI==0 (128x128): Q (pre-scaled) / K direct scatter; V via LDS-transpose.
// EPI==1 (128x64):  fp32 coalesced store to Co.
template<int EPI, int BM, int BN, int CW>
__global__ __launch_bounds__(256)
void gemm_bt(const __bf16* __restrict__ Ag, const __bf16* __restrict__ Bg,
             int M, int N, int K,
             __bf16* __restrict__ Qo, __bf16* __restrict__ Ko, __bf16* __restrict__ Vt,
             float* __restrict__ Co){
  constexpr int AM = BM/32;          // A fragments per wave
  constexpr int AN = BN/32;          // B fragments per wave
  constexpr int CA = BM/64;          // A staging chunks per wave
  constexpr int CB = BN/64;          // B staging chunks per wave
  __shared__ __align__(16) __bf16 As[2][BM*32];
  __shared__ __align__(16) __bf16 Bs[2][BN*32];
  const int tid  = threadIdx.x;
  const int wave = tid >> 6, lane = tid & 63;
  const int wr = wave >> 1, wc = wave & 1;
  const int lr = lane & 15, lg = lane >> 4;

  const int id  = blockIdx.x;
  const int xcd = id & 7;
  const int idx = id >> 3;
  const int nc  = idx / (4*CW);
  const int rem = idx % (4*CW);
  const int m0  = (xcd*4 + rem/CW) * BM;
  const int n0  = (nc*CW + rem%CW) * BN;

  f32x4 acc[AM][AN] = {};

  const int srow = lane >> 2;        // 0..15
  const int scol = (lane & 3) * 8;   // 0,8,16,24
  const __bf16* gA = Ag + (size_t)(m0 + wave*(BM/4) + srow) * K + scol;
  const __bf16* gB = Bg + (size_t)(n0 + wave*(BN/4) + srow) * K + scol;

  const int nk = K >> 5;

  // prologue: stage k-step 0 into buf 0
#pragma unroll
  for (int c = 0; c < CA; c++)
    gload_lds16(gA + (size_t)(c*16)*K, &As[0][(wave*(BM/4) + c*16)*32]);
#pragma unroll
  for (int c = 0; c < CB; c++)
    gload_lds16(gB + (size_t)(c*16)*K, &Bs[0][(wave*(BN/4) + c*16)*32]);

  for (int t = 0; t < nk; t++){
    __syncthreads();                 // drains stage of buf[t&1] (hidden under prev compute)
    if (t + 1 < nk){
      const int k0 = (t+1) << 5, bb = (t+1) & 1;
#pragma unroll
      for (int c = 0; c < CA; c++)
        gload_lds16(gA + k0 + (size_t)(c*16)*K, &As[bb][(wave*(BM/4) + c*16)*32]);
#pragma unroll
      for (int c = 0; c < CB; c++)
        gload_lds16(gB + k0 + (size_t)(c*16)*K, &Bs[bb][(wave*(BN/4) + c*16)*32]);
    }
    const int cb = t & 1;
    bf16x8 af[AM], bfv[AN];
#pragma unroll
    for (int i = 0; i < AM; i++)
      af[i] = *(const bf16x8*)&As[cb][(wr*(BM/2) + i*16 + lr)*32 + lg*8];
#pragma unroll
    for (int j = 0; j < AN; j++)
      bfv[j] = *(const bf16x8*)&Bs[cb][(wc*(BN/2) + j*16 + lr)*32 + lg*8];
#pragma unroll
    for (int i = 0; i < AM; i++)
#pragma unroll
      for (int j = 0; j < AN; j++)
        acc[i][j] = mfma16(af[i], bfv[j], acc[i][j]);
  }

  if (EPI == 0){
    const int three = n0 >> 10;      // block-uniform: 0=Q, 1=K, 2=V
    if (three < 2){
#pragma unroll
      for (int i = 0; i < AM; i++){
#pragma unroll
        for (int j = 0; j < AN; j++){
#pragma unroll
          for (int r = 0; r < 4; r++){
            int m = m0 + wr*(BM/2) + i*16 + lg*4 + r;
            int n = n0 + wc*(BN/2) + j*16 + lr;
            int b = m >> 11, s = m & 2047;
            int h = (n >> 6) & 15, dk = n & 63;
            if (three == 0) Qo[(((size_t)(b*NHEADS + h))*SEQ + s)*DKH + dk] = (__bf16)(acc[i][j][r] * QSCALE);
            else            Ko[(((size_t)(b*NHEADS + h))*SEQ + s)*DKH + dk] = (__bf16)acc[i][j][r];
          }
        }
      }
    } else {
      // V: route acc through LDS, store Vt rows coalesced (32B runs).
      __bf16 (*T)[136] = (__bf16(*)[136])&As[0][0];      // [32 n][128 m] bf16, stride 136
      const int lrow = tid >> 3;          // 0..31 (LDS tile row on read side)
      const int mc   = (tid & 7) * 16;    // m-col base on read side
      const int ngr  = (n0 - 2048) + ((lrow >> 4) << 6) + (lrow & 15);  // + j*16 per chunk
      const int bb   = m0 >> 11;
      const int sbase= (m0 & 2047) + mc;
#pragma unroll
      for (int j = 0; j < AN; j++){
        __syncthreads();                  // prev chunk read done / k-loop LDS reads done
#pragma unroll
        for (int i = 0; i < AM; i++){
          bf16x4 v;
#pragma unroll
          for (int r = 0; r < 4; r++) v[r] = (__bf16)acc[i][j][r];
          *(bf16x4*)&T[wc*16 + lr][wr*64 + i*16 + lg*4] = v;
        }
        __syncthreads();
        const int ng = ngr + j*16;        // 0..1023 within V third
        __bf16* dst = Vt + (((size_t)(bb*NHEADS) + (ng >> 6))*DKH + (ng & 63))*SEQ + sbase;
        bf16x8 x0 = *(const bf16x8*)&T[lrow][mc];
        bf16x8 x1 = *(const bf16x8*)&T[lrow][mc + 8];
        *(bf16x8*)dst = x0;
        *(bf16x8*)(dst + 8) = x1;
      }
    }
  } else {
#pragma unroll
    for (int i = 0; i < AM; i++)
#pragma unroll
      for (int j = 0; j < AN; j++)
#pragma unroll
        for (int r = 0; r < 4; r++){
          int m = m0 + wr*(BM/2) + i*16 + lg*4 + r;
          int n = n0 + wc*(BN/2) + j*16 + lr;
          Co[(size_t)m * N + n] = acc[i][j][r];
        }
  }
}

// ---------------- causal flash attention (R8 structure + in-reg P pack + ones-MFMA l) ----
// Q (pre-scaled), K: [b,h,s,dk] bf16; Vt: [b,h,dk,s] bf16; Aout: [b,s,h*64+dk] bf16
// 64 q-tiles of 32 rows; block handles pair (j, 63-j) -> constant 33 kv-rounds.
// 1024 blocks, 2 waves each; XCD-confined (32 blocks of one bh per XCD, 3MB < L2).
// Double-buffered gload_lds staging (NO reg staging, NO launch_bounds min-waves —
// R9's combo spilled to scratch: VGPR 52, WRITE_SIZE 432MB).
// Row-sum l via ones-column MFMA accumulator lac (every C column = row sum).
__global__ __launch_bounds__(128)
void attn_kernel(const __bf16* __restrict__ Q, const __bf16* __restrict__ K,
                 const __bf16* __restrict__ Vt, __bf16* __restrict__ Aout){
  const int id   = blockIdx.x;               // 0..1023
  const int xcd  = id & 7;
  const int slot = id >> 3;                  // 0..127
  const int bh   = (xcd << 2) | (slot >> 5); // 4 bh per XCD
  const int j    = slot & 31;                // pair index 0..31
  const int wave = threadIdx.x >> 6, lane = threadIdx.x & 63;
  const int lr = lane & 15, lg = lane >> 4;
  const int swz = (lr & 7) << 4;             // read-side XOR

  const __bf16* Qh = Q + (size_t)bh*SEQ*DKH;
  const char* Kc = (const char*)(K  + (size_t)bh*SEQ*DKH);   // row stride 128B
  const char* Vc = (const char*)(Vt + (size_t)bh*DKH*SEQ);   // row stride 4096B

  __shared__ __align__(16) char lds[2][16384];   // [buf][ K 8KB | V 8KB ]

  const int row8 = lane >> 3;
  const int cG   = ((lane & 7) << 4) ^ (row8 << 4);   // pre-swizzled global col

  const int b = bh >> 4, h = bh & 15;

  bf16x8 ONE8;
#pragma unroll
  for (int i = 0; i < 8; i++) ONE8[i] = (__bf16)1.0f;

  for (int ph = 0; ph < 2; ph++){
    const int tb  = ph ? (63 - j) : j;       // 32-row q-tile index
    const int qw  = tb*32 + wave*16;         // wave's first q row
    const int nkv = (tb >> 1) + 1;

    bf16x8 qf0 = *(const bf16x8*)(Qh + (size_t)(qw + lr)*DKH + lg*8);
    bf16x8 qf1 = *(const bf16x8*)(Qh + (size_t)(qw + lr)*DKH + 32 + lg*8);

    f32x4 o[4] = {};
    f32x4 lac = {};                          // row-sum accumulator
    float mrun = -1e30f;

#pragma unroll
    for (int i = 0; i < 4; i++){
      const int srow = wave*32 + i*8 + row8;
      gload_lds16(Kc + (size_t)srow*128 + cG,  &lds[0][wave*4096 + i*1024]);
      gload_lds16(Vc + (size_t)srow*4096 + cG, &lds[0][8192 + wave*4096 + i*1024]);
    }
    __syncthreads();

    for (int kb = 0; kb < nkv; kb++){
      const int kv0 = kb*64;
      if (kb + 1 < nkv){
        const int nv0 = kv0 + 64;
#pragma unroll
        for (int i = 0; i < 4; i++){
          const int srow = wave*32 + i*8 + row8;
          gload_lds16(Kc + (size_t)(nv0 + srow)*128 + cG,
                      &lds[(kb+1)&1][wave*4096 + i*1024]);
          gload_lds16(Vc + (size_t)srow*4096 + (size_t)nv0*2 + cG,
                      &lds[(kb+1)&1][8192 + wave*4096 + i*1024]);
        }
      }
      const char* Ks = lds[kb&1];
      const char* Vs = lds[kb&1] + 8192;

      // ---- QK^T (swapped): sf[t][r] = S[kv0+t*16+lg*4+r][qw+lr] (exp2-domain)
      f32x4 sf[4];
      __builtin_amdgcn_s_setprio(1);
#pragma unroll
      for (int t = 0; t < 4; t++){
        const int row = t*16 + lr;
        bf16x8 kf0 = *(const bf16x8*)(Ks + row*128 + ((lg*16) ^ swz));
        bf16x8 kf1 = *(const bf16x8*)(Ks + row*128 + ((64 + lg*16) ^ swz));
        f32x4 c = {};
        c = mfma16(kf0, qf0, c);
        c = mfma16(kf1, qf1, c);
        sf[t] = c;
      }
      __builtin_amdgcn_s_setprio(0);
      // ---- causal mask (diagonal tiles only)
      if (kv0 + 63 > qw){
        const int q = qw + lr;
#pragma unroll
        for (int t = 0; t < 4; t++)
#pragma unroll
          for (int r = 0; r < 4; r++){
            int kv = kv0 + t*16 + lg*4 + r;
            sf[t][r] = (kv <= q) ? sf[t][r] : -1e30f;
          }
      }
      // ---- row max (max3-friendly tree), then across 4 lanes sharing q-row lr
      float ma = fmaxf(fmaxf(sf[0][0], sf[0][1]), sf[0][2]);
      float mb = fmaxf(fmaxf(sf[0][3], sf[1][0]), sf[1][1]);
      float mc = fmaxf(fmaxf(sf[1][2], sf[1][3]), sf[2][0]);
      float md = fmaxf(fmaxf(sf[2][1], sf[2][2]), sf[2][3]);
      float me = fmaxf(fmaxf(sf[3][0], sf[3][1]), sf[3][2]);
      float mx = fmaxf(fmaxf(ma, mb), mc);
      mx = fmaxf(fmaxf(mx, md), me);
      mx = fmaxf(mx, sf[3][3]);
      mx = fmaxf(mx, __shfl_xor(mx, 16));
      mx = fmaxf(mx, __shfl_xor(mx, 32));

      // ---- T13 defer-rescale: keep old max when growth <= 8 (P <= 2^8, bf16-safe)
      if (!__all(mx <= mrun + 8.0f)){
        float mn = fmaxf(mrun, mx);
        float alpha = __builtin_amdgcn_exp2f(mrun - mn);
        mrun = mn;
        float av[4];
#pragma unroll
        for (int r = 0; r < 4; r++) av[r] = __shfl(alpha, lg*4 + r);
#pragma unroll
        for (int n = 0; n < 4; n++)
#pragma unroll
          for (int r = 0; r < 4; r++) o[n][r] *= av[r];
#pragma unroll
        for (int r = 0; r < 4; r++) lac[r] *= av[r];
      }

      // ---- P = exp2(s-m) packed straight to bf16 A-fragments
      bf16x8 pa0, pa1;
#pragma unroll
      for (int t = 0; t < 2; t++)
#pragma unroll
        for (int r = 0; r < 4; r++)
          pa0[t*4 + r] = (__bf16)__builtin_amdgcn_exp2f(sf[t][r] - mrun);
#pragma unroll
      for (int t = 0; t < 2; t++)
#pragma unroll
        for (int r = 0; r < 4; r++)
          pa1[t*4 + r] = (__bf16)__builtin_amdgcn_exp2f(sf[t+2][r] - mrun);

      // ---- PV + row-sum via ones-column MFMA
      __builtin_amdgcn_s_setprio(1);
      lac = mfma16(pa0, ONE8, lac);
      lac = mfma16(pa1, ONE8, lac);
#pragma unroll
      for (int n = 0; n < 4; n++){
        const int row = n*16 + lr;
        bf16x4 vlo0 = *(const bf16x4*)(Vs + row*128 + ((lg*8) ^ swz));
        bf16x4 vhi0 = *(const bf16x4*)(Vs + row*128 + ((32 + lg*8) ^ swz));
        bf16x4 vlo1 = *(const bf16x4*)(Vs + row*128 + ((64 + lg*8) ^ swz));
        bf16x4 vhi1 = *(const bf16x4*)(Vs + row*128 + ((96 + lg*8) ^ swz));
        bf16x8 vf0 = __builtin_shufflevector(vlo0, vhi0, 0,1,2,3,4,5,6,7);
        bf16x8 vf1 = __builtin_shufflevector(vlo1, vhi1, 0,1,2,3,4,5,6,7);
        o[n] = mfma16(pa0, vf0, o[n]);
        o[n] = mfma16(pa1, vf1, o[n]);
      }
      __builtin_amdgcn_s_setprio(0);
      __syncthreads();                       // tile consumed; next staging safe
    }

    // ---- epilogue: lac[r] = row sum of q = qw+lg*4+r (uniform across lr)
#pragma unroll
    for (int r = 0; r < 4; r++){
      float invr = 1.0f / lac[r];
      __bf16* dst = Aout + ((size_t)b*SEQ + qw + lg*4 + r)*DMODEL + h*DKH;
#pragma unroll
      for (int n = 0; n < 4; n++)
        dst[n*16 + lr] = (__bf16)(o[n][r] * invr);
    }
  }
}

// ---------------- launch ----------------
extern "C" void kernel_launch(void* const* d_in, const int* in_sizes, int n_in,
                              void* d_out, int out_size, void* d_ws, size_t ws_size,
                              hipStream_t stream){
  const float* x    = (const float*)d_in[0];
  const float* wqkv = (const float*)d_in[1];
  const float* wout = (const float*)d_in[2];
  float* out = (float*)d_out;
  char* ws = (char*)d_ws;

  __bf16* xb  = (__bf16*)(ws);                    //  8,388,608  x bf16 [4096,1024]
  __bf16* Ab  = (__bf16*)(ws);                    //  attn out bf16 (alias, x dead)
  __bf16* wqb = (__bf16*)(ws + 8388608);          //  6,291,456  W_qkv bf16
  __bf16* wob = (__bf16*)(ws + 14680064);         //  2,097,152  W_out bf16
  __bf16* Qb  = (__bf16*)(ws + 16777216);         //  8,388,608  Q [b,h,s,dk] (pre-scaled)
  __bf16* Kb  = (__bf16*)(ws + 25165824);         //  8,388,608  K [b,h,s,dk]
  __bf16* Vtb = (__bf16*)(ws + 33554432);         //  8,388,608  V^T [b,h,dk,s]

  cvt3_kernel<<<2048, 256, 0, stream>>>(x, wqkv, wout,
                                        (unsigned short*)xb, (unsigned short*)wqb, (unsigned short*)wob,
                                        (MTOT*DMODEL)/4, (3*DMODEL*DMODEL)/4, (DMODEL*DMODEL)/4);

  // QKV: 96 blocks/XCD, n-chunks of 8 (3MB L2 working set)
  gemm_bt<0,128,128,8><<<768, 256, 0, stream>>>(xb, wqb, MTOT, 3*DMODEL, DMODEL,
                                                Qb, Kb, Vtb, nullptr);
  attn_kernel<<<1024, 128, 0, stream>>>(Qb, Kb, Vtb, Ab);
  // out-proj: CW=16 == all n-blocks (B fits L2)
  gemm_bt<1,128,64,16><<<512, 256, 0, stream>>>(Ab, wob, MTOT, DMODEL, DMODEL,
                                                nullptr, nullptr, nullptr, out);
}